// Round 1
// baseline (944.163 us; speedup 1.0000x reference)
//
#include <hip/hip_runtime.h>

// Problem constants (from reference)
#define F_N 100000
#define C_N 2
#define R_N 500
#define D_N 100            // 25 float4 per feature row
#define NW  3746           // N_WEIGHTS
#define D4  25             // D_N / 4

// BINWIDTHS = {100,200,500,1000,2000,5000}
// BINCUMSTARTS = {0, 2001, 3002, 3403, 3604, 3705}
// Since every bw divides 100000 exactly:
//   bin_ix = (c + 100000)/bw + start   (unsigned div)
//   alpha  = ((c + 100000)%bw) / bw

__global__ __launch_bounds__(256) void spline_enc_kernel(
    const int*   __restrict__ coords,      // (F, 2) int32
    const int*   __restrict__ region_ids,  // (F,)  int32
    const float* __restrict__ W,           // (R, NW, D) fp32
    const float* __restrict__ bias,        // (R, D) fp32
    float*       __restrict__ out)         // (F, D) fp32
{
    const int gid = blockIdx.x * blockDim.x + threadIdx.x;
    const int f = gid / D4;
    const int j = gid % D4;
    if (f >= F_N) return;

    const int r = region_ids[f];

    // clamp coords to [-100000, 99999], shift to unsigned [0, 199999]
    int c0 = coords[2 * f];
    int c1 = coords[2 * f + 1];
    c0 = min(max(c0, -100000), 99999);
    c1 = min(max(c1, -100000), 99999);
    const unsigned u0 = (unsigned)(c0 + 100000);
    const unsigned u1 = (unsigned)(c1 + 100000);

    // base of this region's W, viewed as float4 rows of 25
    const float4* __restrict__ Wr =
        (const float4*)(W + (size_t)r * ((size_t)NW * D_N));
    const float4* __restrict__ br =
        (const float4*)(bias + (size_t)r * D_N);

    float4 acc = br[j];

    const unsigned bws[6]   = {100u, 200u, 500u, 1000u, 2000u, 5000u};
    const int      starts[6] = {0, 2001, 3002, 3403, 3604, 3705};

#pragma unroll
    for (int s = 0; s < 6; ++s) {
        const unsigned bw = bws[s];
        const float inv_bw = 1.0f / (float)bw;
        const int st = starts[s];
#pragma unroll
        for (int c = 0; c < 2; ++c) {
            const unsigned u = (c == 0) ? u0 : u1;
            const unsigned q = u / bw;          // constant divisor -> magic mul
            const unsigned rem = u - q * bw;
            const float alpha = (float)rem * inv_bw;
            const float oma = 1.0f - alpha;
            const size_t row = (size_t)(q + (unsigned)st) * D4 + j;
            const float4 w0 = Wr[row];          // W[r, bin,   j*4 ..]
            const float4 w1 = Wr[row + D4];     // W[r, bin+1, j*4 ..]
            acc.x = fmaf(w0.x, oma, acc.x);
            acc.y = fmaf(w0.y, oma, acc.y);
            acc.z = fmaf(w0.z, oma, acc.z);
            acc.w = fmaf(w0.w, oma, acc.w);
            acc.x = fmaf(w1.x, alpha, acc.x);
            acc.y = fmaf(w1.y, alpha, acc.y);
            acc.z = fmaf(w1.z, alpha, acc.z);
            acc.w = fmaf(w1.w, alpha, acc.w);
        }
    }

    ((float4*)out)[(size_t)f * D4 + j] = acc;
}

extern "C" void kernel_launch(void* const* d_in, const int* in_sizes, int n_in,
                              void* d_out, int out_size, void* d_ws, size_t ws_size,
                              hipStream_t stream) {
    const int*   coords     = (const int*)d_in[0];
    const int*   region_ids = (const int*)d_in[1];
    const float* W          = (const float*)d_in[2];
    const float* bias       = (const float*)d_in[3];
    float*       out        = (float*)d_out;

    const int total = F_N * D4;              // 2,500,000 threads
    const int block = 256;
    const int grid  = (total + block - 1) / block;
    spline_enc_kernel<<<grid, block, 0, stream>>>(coords, region_ids, W, bias, out);
}